// Round 2
// baseline (615.227 us; speedup 1.0000x reference)
//
#include <hip/hip_runtime.h>
#include <stdint.h>
#include <stddef.h>

typedef unsigned short u16;
typedef unsigned int   u32;
typedef __attribute__((ext_vector_type(8))) short          short8;
typedef __attribute__((ext_vector_type(8))) unsigned short ushort8;
typedef __attribute__((ext_vector_type(4))) float          floatx4;
typedef __attribute__((ext_vector_type(4))) int            intx4;

#define NXd 512
#define NUd 32
#define NYd 8
#define Bd  64
#define Td  512
#define BTd (Bd*Td)     /* 32768 */
#define W_IT 7          /* fixed-point sweeps; truncation err <= ~0.25^W */

static __device__ __forceinline__ float bf2f(u16 u){
  union { u32 i; float f; } v; v.i = ((u32)u) << 16; return v.f;
}
static __device__ __forceinline__ u16 f2bf(float f){
  union { float f; u32 i; } v; v.f = f;
  u32 r = v.i + 0x7FFFu + ((v.i >> 16) & 1u);   // RNE
  return (u16)(r >> 16);
}

// ---------------------------------------------------------------------------
// prep: N = I - E (bf16), Hwb = bf16(Hw), Xt0 = (2I - E)^T  (X0 = I + N, stored
// transposed because the NT-GEMM consumes B as [n][k])
// ---------------------------------------------------------------------------
__global__ __launch_bounds__(256) void prep_weights(const float* __restrict__ E,
    const float* __restrict__ Hw, u16* __restrict__ Nb, u16* __restrict__ Hwb,
    u16* __restrict__ Xt0){
  int idx = blockIdx.x*256 + threadIdx.x;        // 2*512*512 total
  int l = idx >> 18;
  int rem = idx & 262143;
  int i = rem >> 9, j = rem & 511;
  float e = E[idx];
  float diag = (i==j) ? 1.f : 0.f;
  Nb[idx]  = f2bf(diag - e);
  Hwb[idx] = f2bf(Hw[idx]);
  float et = E[(l<<18) + (j<<9) + i];            // E[l][j][i]
  Xt0[idx] = f2bf(2.f*diag - et);                // X0^T
}

// ---------------------------------------------------------------------------
// NT GEMM: C[m][n] = sum_k A[m][k] * Bt[n][k], bf16 in / fp32 acc.
// 128x128 tile, BK=64, 4 waves (2x2), 16x16x32 bf16 MFMA.
// EP_NS   : += I, dual store (Xt[n][m] bf16, Xr[m][n] bf16)    [512^3, z=layer]
// EP_TRANS: store MT[n][m] = C[m][n]                           [512^3, z=layer]
// EP_SCAN : v = relu(C + bias[m][n]); store to row m+row_off (guard t==511)
// ---------------------------------------------------------------------------
enum { EP_NS=0, EP_TRANS=1, EP_SCAN=2 };

template<int EPMODE>
__global__ __launch_bounds__(256, 2) void gemm_nt(
    const u16* __restrict__ A, const u16* __restrict__ Bt,
    u16* __restrict__ C, u16* __restrict__ Caux,
    const u16* __restrict__ bias,
    int M, int N, int K, int row_off)
{
  const int tid = threadIdx.x;
  const int bm = blockIdx.x, bn = blockIdx.y, z = blockIdx.z;
  A  += (size_t)z * M * K;
  Bt += (size_t)z * N * K;

  __shared__ u16 As[128][72];   // +8 pad: row stride 144B -> 2-way banks (free)
  __shared__ u16 Bs[128][72];

  const int wave = tid >> 6, lane = tid & 63;
  const int wm = (wave >> 1) * 64, wn = (wave & 1) * 64;
  const int lr = lane & 15, lq = lane >> 4;

  floatx4 acc[4][4];
  #pragma unroll
  for (int i=0;i<4;i++)
    #pragma unroll
    for (int j=0;j<4;j++) acc[i][j] = (floatx4){0.f,0.f,0.f,0.f};

  const int m0 = bm*128, n0 = bn*128;
  for (int kt = 0; kt < K; kt += 64) {
    #pragma unroll
    for (int p=0;p<4;p++){                       // 1024 16B chunks / 256 thr
      int cid = p*256 + tid;
      int r = cid >> 3, c8 = (cid & 7) * 8;
      intx4 va = *(const intx4*)(A  + (size_t)(m0 + r)*K + kt + c8);
      *(intx4*)&As[r][c8] = va;
      intx4 vb = *(const intx4*)(Bt + (size_t)(n0 + r)*K + kt + c8);
      *(intx4*)&Bs[r][c8] = vb;
    }
    __syncthreads();
    #pragma unroll
    for (int kk=0; kk<64; kk+=32) {
      short8 af[4], bf[4];
      #pragma unroll
      for (int i=0;i<4;i++) af[i] = *(const short8*)&As[wm + i*16 + lr][kk + lq*8];
      #pragma unroll
      for (int j=0;j<4;j++) bf[j] = *(const short8*)&Bs[wn + j*16 + lr][kk + lq*8];
      #pragma unroll
      for (int i=0;i<4;i++)
        #pragma unroll
        for (int j=0;j<4;j++)
          acc[i][j] = __builtin_amdgcn_mfma_f32_16x16x32_bf16(af[i], bf[j], acc[i][j], 0,0,0);
    }
    __syncthreads();
  }

  #pragma unroll
  for (int i=0;i<4;i++){
    #pragma unroll
    for (int j=0;j<4;j++){
      #pragma unroll
      for (int r=0;r<4;r++){
        int grow = m0 + wm + i*16 + lq*4 + r;    // C/D: row=(lane>>4)*4+reg
        int gcol = n0 + wn + j*16 + lr;          //      col=lane&15
        float v = acc[i][j][r];
        if (EPMODE == EP_NS) {
          v += (grow == gcol) ? 1.f : 0.f;
          u16 b = f2bf(v);
          C[(size_t)z*M*N + (size_t)gcol*N + grow]    = b;   // Xt[n][m]
          Caux[(size_t)z*M*N + (size_t)grow*N + gcol] = b;   // Xr[m][n]
        } else if (EPMODE == EP_TRANS) {
          C[(size_t)z*M*N + (size_t)gcol*N + grow] = f2bf(v); // MT[n][m]
        } else { // EP_SCAN
          float bv = bf2f(bias[(size_t)grow*N + gcol]);
          v += bv;
          v = v > 0.f ? v : 0.f;
          if (row_off == 0 || (grow & (Td-1)) != (Td-1))
            C[(size_t)(grow + row_off)*N + gcol] = f2bf(v);
        }
      }
    }
  }
}

// ---------------------------------------------------------------------------
// Cw1[k][n] = sum_p Einv1[k][p] * Cw[n][p]   (fp32 out, 512x8)
// ---------------------------------------------------------------------------
__global__ __launch_bounds__(256) void cw1_kernel(const u16* __restrict__ Xr,
    const float* __restrict__ Cw, float* __restrict__ Cw1){
  int idx = blockIdx.x*256 + threadIdx.x;        // 4096
  int k = idx >> 3, n = idx & 7;
  const u16*  xrow = Xr + (size_t)NXd*NXd + (size_t)k*NXd;   // layer 1
  const float* crow = Cw + (size_t)n*NXd;
  float acc = 0.f;
  for (int p=0;p<NXd;p++) acc += bf2f(xrow[p]) * crow[p];
  Cw1[idx] = acc;
}

// ---------------------------------------------------------------------------
// U_l[b,t,n] = bf16( sum_j u[b,j,t]*Kw[l][n][j] + Hb[l][n] ), both layers.
// grid (64 b, 2 n-chunks of 256, 8 t-chunks of 64)
// ---------------------------------------------------------------------------
__global__ __launch_bounds__(256) void u_proj(const float* __restrict__ u,
    const float* __restrict__ Kw, const float* __restrict__ Hb,
    u16* __restrict__ U0, u16* __restrict__ U1){
  int b = blockIdx.x, nc = blockIdx.y, tc = blockIdx.z;
  int tid = threadIdx.x;
  int n = nc*256 + tid;
  int t0 = tc*64;
  __shared__ float us[NUd][64];
  #pragma unroll
  for (int p=0;p<8;p++){
    int cid = p*256 + tid;
    int j = cid >> 6, tt2 = cid & 63;
    us[j][tt2] = u[(size_t)b*NUd*Td + (size_t)j*Td + t0 + tt2];
  }
  float kw0[NUd], kw1[NUd];
  #pragma unroll
  for (int j=0;j<NUd;j++){
    kw0[j] = Kw[(size_t)n*NUd + j];
    kw1[j] = Kw[(size_t)(NXd + n)*NUd + j];
  }
  float hb0 = Hb[n], hb1 = Hb[NXd + n];
  __syncthreads();
  for (int tt=0; tt<64; tt++){
    float a0 = hb0, a1 = hb1;
    #pragma unroll
    for (int j=0;j<NUd;j++){ float uv = us[j][tt]; a0 += uv*kw0[j]; a1 += uv*kw1[j]; }
    size_t o = ((size_t)b*Td + t0 + tt)*NXd + n;
    U0[o] = f2bf(a0); U1[o] = f2bf(a1);
  }
}

// E0^{(1)} = relu(U0)  (bitwise bf16 relu, uint4-wide)
static __device__ __forceinline__ u32 relu2(u32 w){
  u32 lo = (w & 0x8000u)     ? 0u : (w & 0xFFFFu);
  u32 hi = (w & 0x80000000u) ? 0u : (w & 0xFFFF0000u);
  return lo | hi;
}
__global__ __launch_bounds__(256) void relu_copy4(const uint4* __restrict__ U,
    uint4* __restrict__ E, int n){
  int i = blockIdx.x*256 + threadIdx.x, stride = gridDim.x*256;
  for (; i < n; i += stride){
    uint4 v = U[i];
    v.x = relu2(v.x); v.y = relu2(v.y); v.z = relu2(v.z); v.w = relu2(v.w);
    E[i] = v;
  }
}

// zero E1buf slot 0 per batch (h_{-1} = 0): 64 rows x 512 bf16 = 4096 uint4
__global__ __launch_bounds__(256) void zero_slot0(uint4* __restrict__ E1){
  int idx = blockIdx.x*256 + threadIdx.x;
  if (idx < 4096){
    int b = idx >> 6, c = idx & 63;
    E1[(size_t)b*(Td*NXd/8) + c] = (uint4){0,0,0,0};
  }
}

// ---------------------------------------------------------------------------
// y[b,n,t] = E0[b,t,:] @ Cw1[:,n] + Cb[n]  (t<511), y[b,n,511] = Cb[n]
// OUTPUT IS FLOAT32 (reference computes in f32; harness d_out is float*).
// one wave per row, 8 rows per wave; Cw1 kept in registers (8k x 8n per lane)
// ---------------------------------------------------------------------------
__global__ __launch_bounds__(256) void out_proj(const u16* __restrict__ E0,
    const float* __restrict__ Cw1, const float* __restrict__ Cb,
    float* __restrict__ out){
  int wave = threadIdx.x >> 6, lane = threadIdx.x & 63;
  float cw[8][8];
  #pragma unroll
  for (int j=0;j<8;j++){
    const floatx4* p = (const floatx4*)(Cw1 + (size_t)(lane*8 + j)*8);
    floatx4 a = p[0], b2 = p[1];
    cw[j][0]=a[0]; cw[j][1]=a[1]; cw[j][2]=a[2]; cw[j][3]=a[3];
    cw[j][4]=b2[0]; cw[j][5]=b2[1]; cw[j][6]=b2[2]; cw[j][7]=b2[3];
  }
  float cb[8];
  #pragma unroll
  for (int nn=0;nn<8;nn++) cb[nn] = Cb[nn];
  int rowbase = (blockIdx.x*4 + wave) * 8;
  for (int rr=0; rr<8; rr++){
    int row = rowbase + rr;                 // = b*512 + t
    int t = row & (Td-1), b = row >> 9;
    ushort8 ev = *(const ushort8*)(E0 + (size_t)row*NXd + lane*8);
    float acc[8];
    #pragma unroll
    for (int nn=0;nn<8;nn++) acc[nn] = 0.f;
    #pragma unroll
    for (int j=0;j<8;j++){
      float a = bf2f(ev[j]);
      #pragma unroll
      for (int nn=0;nn<8;nn++) acc[nn] += a * cw[j][nn];
    }
    #pragma unroll
    for (int nn=0;nn<8;nn++){
      #pragma unroll
      for (int off=32; off; off>>=1) acc[nn] += __shfl_xor(acc[nn], off, 64);
    }
    if (lane < 8){
      float y = (t == Td-1) ? cb[lane] : (acc[lane] + cb[lane]);
      out[(size_t)b*NYd*Td + (size_t)lane*Td + t] = y;   // f32 store
    }
  }
}

// ---------------------------------------------------------------------------
extern "C" void kernel_launch(void* const* d_in, const int* in_sizes, int n_in,
                              void* d_out, int out_size, void* d_ws, size_t ws_size,
                              hipStream_t stream) {
  const float* u  = (const float*)d_in[0];
  const float* E  = (const float*)d_in[1];
  const float* Hw = (const float*)d_in[2];
  const float* Hb = (const float*)d_in[3];
  const float* Kw = (const float*)d_in[4];
  const float* Cw = (const float*)d_in[5];
  const float* Cb = (const float*)d_in[6];
  float* out = (float*)d_out;

  // workspace carve-up (elements of u16 unless noted); ~137 MB total
  u16* U0  = (u16*)d_ws;                  // 32 MB  [BT][NX]  u@Kw0^T + b0
  u16* U1  = U0 + (size_t)BTd*NXd;        // 32 MB
  u16* E0  = U1 + (size_t)BTd*NXd;        // 32 MB  e0 tensor
  u16* E1  = E0 + (size_t)BTd*NXd;        // 32 MB  e1 tensor, slot = t+1
  u16* Nb  = E1 + (size_t)BTd*NXd;        // 1 MB   [2][512][512]  I-E
  u16* Hwb = Nb  + (size_t)2*NXd*NXd;     // 1 MB   bf16(Hw)
  u16* Xt0 = Hwb + (size_t)2*NXd*NXd;     // 1 MB   X^T ping
  u16* Xt1 = Xt0 + (size_t)2*NXd*NXd;     // 1 MB   X^T pong
  u16* Xr  = Xt1 + (size_t)2*NXd*NXd;     // 1 MB   X row-major (final Einv)
  u16* MT  = Xr  + (size_t)2*NXd*NXd;     // 1 MB   M_l transposed [n][k]
  float* Cw1 = (float*)(MT + (size_t)2*NXd*NXd);  // 16 KB

  prep_weights<<<2048, 256, 0, stream>>>(E, Hw, Nb, Hwb, Xt0);

  // Einv via Neumann-Horner: X <- I + N@X  (4 steps, ping-pong X^T)
  dim3 g512(4,4,2);
  gemm_nt<EP_NS><<<g512,256,0,stream>>>(Nb, Xt0, Xt1, Xr, nullptr, 512,512,512, 0);
  gemm_nt<EP_NS><<<g512,256,0,stream>>>(Nb, Xt1, Xt0, Xr, nullptr, 512,512,512, 0);
  gemm_nt<EP_NS><<<g512,256,0,stream>>>(Nb, Xt0, Xt1, Xr, nullptr, 512,512,512, 0);
  gemm_nt<EP_NS><<<g512,256,0,stream>>>(Nb, Xt1, Xt0, Xr, nullptr, 512,512,512, 0);

  // M_l = Einv_l @ Hw_l^T, stored transposed [n][k]
  gemm_nt<EP_TRANS><<<g512,256,0,stream>>>(Xr, Hwb, MT, nullptr, nullptr, 512,512,512, 0);
  // Cw1 = Einv1 @ Cw^T
  cw1_kernel<<<16,256,0,stream>>>(Xr, Cw, Cw1);

  // input projections (incl. Hb), bf16
  u_proj<<<dim3(64,2,8),256,0,stream>>>(u, Kw, Hb, U0, U1);

  // iteration 1 bootstrap: E0 = relu(U0); E1 slot0 = 0
  relu_copy4<<<2048,256,0,stream>>>((const uint4*)U0, (uint4*)E0, BTd*NXd/8);
  zero_slot0<<<16,256,0,stream>>>((uint4*)E1);

  // fixed-point sweeps: E0 <- relu(E1shift@M0 + U0); E1 <- relu(E0@M1 + U1)
  const u16* MT0 = MT;
  const u16* MT1 = MT + (size_t)NXd*NXd;
  dim3 gs(BTd/128, NXd/128, 1);
  for (int it = 0; it < W_IT; it++){
    if (it > 0)
      gemm_nt<EP_SCAN><<<gs,256,0,stream>>>(E1, MT0, E0, nullptr, U0, BTd, NXd, NXd, 0);
    gemm_nt<EP_SCAN><<<gs,256,0,stream>>>(E0, MT1, E1, nullptr, U1, BTd, NXd, NXd, 1);
  }

  out_proj<<<BTd/32, 256, 0, stream>>>(E0, Cw1, Cb, out);
}